// Round 10
// baseline (253.075 us; speedup 1.0000x reference)
//
#include <hip/hip_runtime.h>

// h = x(65536x512) @ W^T(512x256) + bias_lin ; GroupNorm(8 groups of 32)
// ; min over 256 channels -> m[b] ; out[c*B+b] = m[b] + bias[c]
//
// R10: non-persistent many-block design. All prior rounds ran ONE lockstep
// barrier group per CU (W-in-registers capped residency at one block), so
// stage/K-loop/stats phases serialized on the barrier chain; R9's split
// isolated the pacer to this read/compute side (~67us at 2 TB/s, all pipes
// <15%). Now: 8192 blocks x 256 thr (4 waves); block = one 32-row tile x
// 64 channels (wave owns 1 nt -> bfr=64 VGPR -> ~128-reg class -> 16
// waves/CU = 4 INDEPENDENT blocks resident; LDS 33KB x4 = 133KB). Four
// blocks per tile pinned to the same XCD (round-robin map: xcd=bid&7) so
// X is HBM-fetched once and L2-served 3x. Per-block 64-ch partial min ->
// mpart[4][65536]; bcast_out takes 4-way min + bias.
#define B_ROWS 65536
#define K_DIM  512
#define N_DIM  256
#define EPS    1e-5f
#define MTILE  32
#define TILES  (B_ROWS / MTILE)       // 2048
#define STRIDE 520                    // 512 + 8 pad (bf16)

using short8  = __attribute__((ext_vector_type(8))) short;
using floatx4 = __attribute__((ext_vector_type(4))) float;

__device__ __forceinline__ unsigned short f2bf(float f) {
    unsigned u = __builtin_bit_cast(unsigned, f);
    u += 0x7FFFu + ((u >> 16) & 1u);     // RNE
    return (unsigned short)(u >> 16);
}

// Pack W (256x512 fp32) into bf16 MFMA fragment order (A/B layouts symmetric
// for 16x16x32):
// P[((nt*16 + kkg)*64 + lane)*8 + j] = bf16(W[nt*16 + (lane&15)][kkg*32 + (lane>>4)*8 + j])
__global__ __launch_bounds__(64) void pack_w(const float* __restrict__ W,
                                             unsigned short* __restrict__ P) {
    int b    = blockIdx.x;           // 0..255
    int nt   = b >> 4, kk = b & 15;
    int lane = threadIdx.x;
    int l15  = lane & 15, quad = lane >> 4;
    const float* src = W + (size_t)(nt * 16 + l15) * K_DIM + kk * 32 + quad * 8;
    short8 v;
#pragma unroll
    for (int j = 0; j < 8; ++j) v[j] = (short)f2bf(src[j]);
    *(short8*)(P + ((size_t)(nt * 16 + kk) * 64 + lane) * 8) = v;
}

// One block = one 32-row tile x 64 channels (part). 4 waves, wave w owns
// nt = part*4 + w. GN group (32 ch) = wave pair (w, w^1) via LDS exchange.
__global__ __launch_bounds__(256, 4) void gemm_gn_minpart(
    const float* __restrict__ X, const unsigned short* __restrict__ P,
    const float* __restrict__ bias_lin, const float* __restrict__ wgn,
    const float* __restrict__ bgn, float* __restrict__ mparts)
{
    __shared__ unsigned short Ash[MTILE * STRIDE];   // 33280 B
    __shared__ float smS[4][32];
    __shared__ float smSS[4][32];
    __shared__ float smin[4][32];

    const int tid  = threadIdx.x;
    const int wave = tid >> 6;            // 0..3
    const int lane = tid & 63;
    const int l15  = lane & 15, quad = lane >> 4;

    // XCD-affine tile decomposition: dispatch round-robins XCD = bid & 7.
    const int bid  = blockIdx.x;          // 0..8191
    const int xcd  = bid & 7;
    const int j    = bid >> 3;            // 0..1023
    const int tile = xcd * 256 + (j >> 2);
    const int part = j & 3;
    const int nt   = part * 4 + wave;     // 0..15; channels [nt*16, nt*16+16)

    // ---- issue W-fragment loads early (L2-hot after first blocks) ----
    short8 bfr[16];
#pragma unroll
    for (int kkg = 0; kkg < 16; ++kkg)
        bfr[kkg] = *(const short8*)(P + (((size_t)nt * 16 + kkg) * 64 + lane) * 8);

    // per-lane channel params: ch = nt*16 + quad*4 + r
    float blr[4], wgr[4], bgr[4];
#pragma unroll
    for (int r = 0; r < 4; ++r) {
        int c = nt * 16 + quad * 4 + r;
        blr[r] = bias_lin[c]; wgr[r] = wgn[c]; bgr[r] = bgn[c];
    }

    // ---- stage tile into LDS: thread covers rows r0..r0+15 (r0=(tid>>7)*16)
    //      at fp32 cols [c4, c4+4); per-instruction wave access = 1KB
    //      consecutive on one row (perfectly coalesced) ----
    {
        const int r0 = (tid >> 7) * 16;
        const int c4 = (tid & 127) * 4;
        const float* src = X + (size_t)(tile * MTILE + r0) * K_DIM + c4;
#pragma unroll
        for (int p = 0; p < 16; ++p) {
            float4 v = *(const float4*)(src + (size_t)p * K_DIM);
            ushort4 h;
            h.x = f2bf(v.x); h.y = f2bf(v.y); h.z = f2bf(v.z); h.w = f2bf(v.w);
            *(ushort4*)(&Ash[(r0 + p) * STRIDE + c4]) = h;
        }
    }
    __syncthreads();

    // ---- K-loop: D[ch16][row32] = W·X^T, bias in C-init ----
    floatx4 acc[2];
#pragma unroll
    for (int rt = 0; rt < 2; ++rt)
#pragma unroll
        for (int r = 0; r < 4; ++r) acc[rt][r] = blr[r];
#pragma unroll
    for (int kk = 0; kk < 16; ++kk) {
        short8 a0 = *(const short8*)&Ash[(l15)      * STRIDE + kk * 32 + quad * 8];
        short8 a1 = *(const short8*)&Ash[(16 + l15) * STRIDE + kk * 32 + quad * 8];
        acc[0] = __builtin_amdgcn_mfma_f32_16x16x32_bf16(bfr[kk], a0, acc[0], 0, 0, 0);
        acc[1] = __builtin_amdgcn_mfma_f32_16x16x32_bf16(bfr[kk], a1, acc[1], 0, 0, 0);
    }

    // ---- GroupNorm stats: in-lane over 4 ch + quad shfl -> wave's 16 ch;
    //      combine with partner wave (wave^1) via LDS ----
    float sreg[2], ssreg[2];
#pragma unroll
    for (int rt = 0; rt < 2; ++rt) {
        float s = 0.f, ss = 0.f;
#pragma unroll
        for (int r = 0; r < 4; ++r) { float v = acc[rt][r]; s += v; ss = fmaf(v, v, ss); }
        s  += __shfl_xor(s, 16);  s  += __shfl_xor(s, 32);
        ss += __shfl_xor(ss, 16); ss += __shfl_xor(ss, 32);
        sreg[rt] = s; ssreg[rt] = ss;
        if (quad == 0) { smS[wave][rt * 16 + l15] = s; smSS[wave][rt * 16 + l15] = ss; }
    }
    __syncthreads();

#pragma unroll
    for (int rt = 0; rt < 2; ++rt) {
        int row = rt * 16 + l15;
        float st   = sreg[rt]  + smS[wave ^ 1][row];    // 32-ch sums
        float sst  = ssreg[rt] + smSS[wave ^ 1][row];
        float mean = st * (1.0f / 32.0f);
        float var  = sst * (1.0f / 32.0f) - mean * mean;
        float inv  = rsqrtf(var + EPS);
        float mi   = mean * inv;
        float mn   = 1e30f;
#pragma unroll
        for (int r = 0; r < 4; ++r) {
            float g = fmaf(fmaf(acc[rt][r], inv, -mi), wgr[r], bgr[r]);
            mn = fminf(mn, g);
        }
        mn = fminf(mn, __shfl_xor(mn, 16));
        mn = fminf(mn, __shfl_xor(mn, 32));
        if (quad == 0) smin[wave][row] = mn;
    }
    __syncthreads();

    // ---- block's 64-ch partial min -> mpart[part] ----
    if (tid < MTILE) {
        float m0 = fminf(fminf(smin[0][tid], smin[1][tid]),
                         fminf(smin[2][tid], smin[3][tid]));
        mparts[(size_t)part * B_ROWS + tile * MTILE + tid] = m0;
    }
}

// out[c*B + b] = min(mp0..mp3)[b] + bias[c]; channel constant per block.
__global__ __launch_bounds__(256) void bcast_out(
    const float* __restrict__ mparts, const float* __restrict__ bias,
    float* __restrict__ out)
{
    const float4* m0 = (const float4*)(mparts);
    const float4* m1 = (const float4*)(mparts + B_ROWS);
    const float4* m2 = (const float4*)(mparts + 2 * B_ROWS);
    const float4* m3 = (const float4*)(mparts + 3 * B_ROWS);
    float4*       o4 = (float4*)out;
    const int bid = blockIdx.x;          // 0..2047
    const int c   = bid >> 3;            // 8 blocks per channel
    const float bc = bias[c];
    const int base = (bid & 7) * 2048;   // float4 offset within channel
#pragma unroll
    for (int k = 0; k < 8; ++k) {
        int idx = base + k * 256 + threadIdx.x;          // 0..16383
        float4 a = m0[idx], b = m1[idx], d = m2[idx], e = m3[idx];
        float4 o;
        o.x = fminf(fminf(a.x, b.x), fminf(d.x, e.x)) + bc;
        o.y = fminf(fminf(a.y, b.y), fminf(d.y, e.y)) + bc;
        o.z = fminf(fminf(a.z, b.z), fminf(d.z, e.z)) + bc;
        o.w = fminf(fminf(a.w, b.w), fminf(d.w, e.w)) + bc;
        o4[(size_t)c * (B_ROWS / 4) + idx] = o;
    }
}

extern "C" void kernel_launch(void* const* d_in, const int* in_sizes, int n_in,
                              void* d_out, int out_size, void* d_ws, size_t ws_size,
                              hipStream_t stream) {
    const float* x    = (const float*)d_in[0];
    const float* w    = (const float*)d_in[1];
    const float* bl   = (const float*)d_in[2];
    const float* wg   = (const float*)d_in[3];
    const float* bg   = (const float*)d_in[4];
    const float* bias = (const float*)d_in[5];

    unsigned short* P = (unsigned short*)d_ws;                 // 256 KB packed bf16 W
    float* mparts     = (float*)((char*)d_ws + 262144);        // 4 x 256 KB partial mins
    float* out        = (float*)d_out;

    hipLaunchKernelGGL(pack_w, dim3(256), dim3(64), 0, stream, w, P);
    hipLaunchKernelGGL(gemm_gn_minpart, dim3(8192), dim3(256), 0, stream,
                       x, P, bl, wg, bg, mparts);
    hipLaunchKernelGGL(bcast_out, dim3(2048), dim3(256), 0, stream, mparts, bias, out);
}